// Round 2
// baseline (352.935 us; speedup 1.0000x reference)
//
#include <hip/hip_runtime.h>
#include <math.h>

#define UNITS  512
#define BATCH  32
#define SEQ    4096
#define CHUNKS 64
#define RPC    (SEQ / CHUNKS)   // 64 rows per chunk

// workspace layout (float offsets)
#define OFF_UV    0                       // 512
#define OFF_WV    512                     // 512
#define OFF_PP    1024                    // pp[b*32+i]  (32 batches x 32 prep-blocks)
#define OFF_CB    2048                    // 1 scalar
#define OFF_CNT   2056                    // 32 uint32 completion counters
#define OFF_PSUM  4096                    // BATCH*CHUNKS = 2048
#define OFF_PCTX  8192                    // BATCH*CHUNKS*UNITS = 1,048,576 (~4 MB)

__device__ inline float wave_reduce_add(float v) {
#pragma unroll
    for (int off = 32; off >= 1; off >>= 1) v += __shfl_xor(v, off);
    return v;
}

__device__ inline float dot8(float4 a, float4 b, float4 u0, float4 u1) {
    return a.x*u0.x + a.y*u0.y + a.z*u0.z + a.w*u0.w
         + b.x*u1.x + b.y*u1.y + b.z*u1.z + b.w*u1.w;
}

// K0 (32 blocks): uv/wv rows, pbias partials pp[b][block], cb, zero counters.
__global__ __launch_bounds__(256) void k_prep(const float* __restrict__ Ww,
                                              const float* __restrict__ Uw,
                                              const float* __restrict__ Vw,
                                              const float* __restrict__ Wb,
                                              const float* __restrict__ Ub,
                                              const float* __restrict__ Vb,
                                              const float* __restrict__ s_prev,
                                              float* __restrict__ ws) {
    int tid = threadIdx.x, wave = tid >> 6, lane = tid & 63;
    float4 v0 = *(const float4*)(Vw + lane * 8);
    float4 v1 = *(const float4*)(Vw + lane * 8 + 4);
    int rowbase = blockIdx.x * 16;

    for (int i = wave; i < 16; i += 4) {
        int u = rowbase + i;
        const float* ur = Uw + (size_t)u * UNITS + lane * 8;
        float4 a = *(const float4*)ur;
        float4 b = *(const float4*)(ur + 4);
        float d = wave_reduce_add(dot8(a, b, v0, v1));
        if (lane == 0) ws[OFF_UV + u] = d;
        const float* wr = Ww + (size_t)u * UNITS + lane * 8;
        a = *(const float4*)wr;
        b = *(const float4*)(wr + 4);
        d = wave_reduce_add(dot8(a, b, v0, v1));
        if (lane == 0) ws[OFF_WV + u] = d;
    }

    if (blockIdx.x == 0) {
        if (tid < BATCH) ((unsigned*)(ws + OFF_CNT))[tid] = 0u;
        float part = 0.f;
        for (int v = tid; v < UNITS; v += 256) part += (Wb[v] + Ub[v]) * Vw[v];
        part = wave_reduce_add(part);
        __shared__ float wred[4];
        if (lane == 0) wred[wave] = part;
        __syncthreads();
        if (tid == 0) ws[OFF_CB] = wred[0] + wred[1] + wred[2] + wred[3] + Vb[0];
    }

    __syncthreads();  // wv rows of this block now visible block-wide

    // pp[b][blockIdx.x] = sum_{j=0..15} s_prev[b, rowbase+j] * wv[rowbase+j]
    int b = tid >> 3;      // 0..31
    int g = tid & 7;       // 0..7 -> j = g, g+8
    int ua = rowbase + g, ub = rowbase + g + 8;
    float p = s_prev[(size_t)b * UNITS + ua] * ws[OFF_WV + ua]
            + s_prev[(size_t)b * UNITS + ub] * ws[OFF_WV + ub];
    p += __shfl_xor(p, 1);
    p += __shfl_xor(p, 2);
    p += __shfl_xor(p, 4);
    if (g == 0) ws[OFF_PP + b * 32 + blockIdx.x] = p;
}

// K1 (CHUNKS x BATCH blocks): stream h once; p=exp(tanh(h.uv+pb)) to out
// (unnormalized); partial Z and partial context to ws; last block per batch
// finalizes: Z, context write, in-place weight scaling.
__global__ __launch_bounds__(256) void k_main(const float* __restrict__ h,
                                              float* __restrict__ ws,
                                              float* __restrict__ out) {
    int chunk = blockIdx.x, b = blockIdx.y;
    int tid = threadIdx.x, wave = tid >> 6, lane = tid & 63;

    // reconstruct pb = sum_i pp[b][i] + cb (L2-resident, ~1 load/lane)
    __shared__ float pbsh;
    {
        float p = (lane < 32) ? ws[OFF_PP + b * 32 + lane] : 0.f;
        p = wave_reduce_add(p);
        if (tid == 0) pbsh = p + ws[OFF_CB];
    }
    float4 u0 = *(const float4*)(ws + OFF_UV + lane * 8);
    float4 u1 = *(const float4*)(ws + OFF_UV + lane * 8 + 4);
    __syncthreads();
    float pb = pbsh;

    float4 acc0 = make_float4(0.f, 0.f, 0.f, 0.f);
    float4 acc1 = make_float4(0.f, 0.f, 0.f, 0.f);
    float zs = 0.f;

    const float* hb = h + ((size_t)b * SEQ + (size_t)chunk * RPC) * UNITS + lane * 8;
    float* pout = out + (size_t)BATCH * UNITS + (size_t)b * SEQ + (size_t)chunk * RPC;

    for (int r = wave; r < RPC; r += 8) {
        const float* r0 = hb + (size_t)r * UNITS;
        const float* r1 = hb + (size_t)(r + 4) * UNITS;
        float4 a0 = *(const float4*)r0;
        float4 b0 = *(const float4*)(r0 + 4);
        float4 a1 = *(const float4*)r1;
        float4 b1 = *(const float4*)(r1 + 4);

        float d0 = dot8(a0, b0, u0, u1);
        float d1 = dot8(a1, b1, u0, u1);
#pragma unroll
        for (int off = 32; off >= 1; off >>= 1) {
            d0 += __shfl_xor(d0, off);
            d1 += __shfl_xor(d1, off);
        }
        float w0 = __expf(tanhf(d0 + pb));
        float w1 = __expf(tanhf(d1 + pb));
        if (lane == 0) { pout[r] = w0; pout[r + 4] = w1; }
        zs += w0 + w1;
        acc0.x += w0 * a0.x + w1 * a1.x;
        acc0.y += w0 * a0.y + w1 * a1.y;
        acc0.z += w0 * a0.z + w1 * a1.z;
        acc0.w += w0 * a0.w + w1 * a1.w;
        acc1.x += w0 * b0.x + w1 * b1.x;
        acc1.y += w0 * b0.y + w1 * b1.y;
        acc1.z += w0 * b0.z + w1 * b1.z;
        acc1.w += w0 * b0.w + w1 * b1.w;
    }

    __shared__ float lctx[4][UNITS];
    __shared__ float lsum[4];
    *(float4*)&lctx[wave][lane * 8]     = acc0;
    *(float4*)&lctx[wave][lane * 8 + 4] = acc1;
    if (lane == 0) lsum[wave] = zs;
    __syncthreads();

    float* pc = ws + OFF_PCTX + ((size_t)(b * CHUNKS + chunk)) * UNITS;
    for (int col = tid; col < UNITS; col += 256)
        pc[col] = lctx[0][col] + lctx[1][col] + lctx[2][col] + lctx[3][col];
    if (tid == 0)
        ws[OFF_PSUM + b * CHUNKS + chunk] = lsum[0] + lsum[1] + lsum[2] + lsum[3];

    // release: make this block's partials + p visible, then count completion
    __threadfence();
    __syncthreads();
    __shared__ unsigned olds;
    if (tid == 0) olds = atomicAdd((unsigned*)(ws + OFF_CNT) + b, 1u);
    __syncthreads();

    if (olds == CHUNKS - 1) {   // block-uniform: this block finalizes batch b
        __threadfence();        // acquire
        __shared__ float zsh;
        if (wave == 0) {
            float z = ws[OFF_PSUM + b * CHUNKS + lane];   // CHUNKS == 64 lanes
            z = wave_reduce_add(z);
            if (lane == 0) zsh = 1.0f / z;
        }
        __syncthreads();
        float rz = zsh;

        for (int col = tid; col < UNITS; col += 256) {
            float s = 0.f;
#pragma unroll
            for (int c = 0; c < CHUNKS; c++)
                s += ws[OFF_PCTX + (size_t)(b * CHUNKS + c) * UNITS + col];
            out[(size_t)b * UNITS + col] = s * rz;
        }

        float* wout = out + (size_t)BATCH * UNITS + (size_t)b * SEQ;
        for (int s2 = tid; s2 < SEQ; s2 += 256) wout[s2] *= rz;
    }
}

extern "C" void kernel_launch(void* const* d_in, const int* in_sizes, int n_in,
                              void* d_out, int out_size, void* d_ws, size_t ws_size,
                              hipStream_t stream) {
    (void)in_sizes; (void)n_in; (void)out_size; (void)ws_size;
    const float* s_prev = (const float*)d_in[0];
    const float* h      = (const float*)d_in[1];
    const float* Ww     = (const float*)d_in[2];
    const float* Wb     = (const float*)d_in[3];
    const float* Uw     = (const float*)d_in[4];
    const float* Ub     = (const float*)d_in[5];
    const float* Vw     = (const float*)d_in[6];
    const float* Vb     = (const float*)d_in[7];
    float* out = (float*)d_out;
    float* ws  = (float*)d_ws;

    hipLaunchKernelGGL(k_prep, dim3(32),            dim3(256), 0, stream,
                       Ww, Uw, Vw, Wb, Ub, Vb, s_prev, ws);
    hipLaunchKernelGGL(k_main, dim3(CHUNKS, BATCH), dim3(256), 0, stream,
                       h, ws, out);
}

// Round 3
// 57.193 us; speedup vs baseline: 6.1710x; 6.1710x over previous
//
#include <hip/hip_runtime.h>
#include <math.h>

#define UNITS  512
#define BATCH  32
#define SEQ    4096
#define CHUNKS 32
#define RPC    (SEQ / CHUNKS)   // 128 rows per chunk

// workspace layout (float offsets)
#define OFF_UV    0                       // 512
#define OFF_WV    512                     // 512
#define OFF_PP    1024                    // pp[b*32+blk]  (32 x 32)
#define OFF_CB    2048                    // 1 scalar
#define OFF_PSUM  4096                    // BATCH*CHUNKS = 1024
#define OFF_PCTX  8192                    // BATCH*CHUNKS*UNITS = 524288 (~2 MB)

__device__ inline float wave_reduce_add(float v) {
#pragma unroll
    for (int off = 32; off >= 1; off >>= 1) v += __shfl_xor(v, off);
    return v;
}

__device__ inline float dot8(float4 a, float4 b, float4 u0, float4 u1) {
    return a.x*u0.x + a.y*u0.y + a.z*u0.z + a.w*u0.w
         + b.x*u1.x + b.y*u1.y + b.z*u1.z + b.w*u1.w;
}

// K0 (32 blocks): uv/wv rows, cb scalar, pbias partials pp[b][block].
// Kernel boundary provides device-wide visibility to k_main (no fences).
__global__ __launch_bounds__(256) void k_prep(const float* __restrict__ Ww,
                                              const float* __restrict__ Uw,
                                              const float* __restrict__ Vw,
                                              const float* __restrict__ Wb,
                                              const float* __restrict__ Ub,
                                              const float* __restrict__ Vb,
                                              const float* __restrict__ s_prev,
                                              float* __restrict__ ws) {
    int tid = threadIdx.x, wave = tid >> 6, lane = tid & 63;
    float4 v0 = *(const float4*)(Vw + lane * 8);
    float4 v1 = *(const float4*)(Vw + lane * 8 + 4);
    int rowbase = blockIdx.x * 16;

    for (int i = wave; i < 16; i += 4) {
        int u = rowbase + i;
        const float* ur = Uw + (size_t)u * UNITS + lane * 8;
        float4 a = *(const float4*)ur;
        float4 b = *(const float4*)(ur + 4);
        float d = wave_reduce_add(dot8(a, b, v0, v1));
        if (lane == 0) ws[OFF_UV + u] = d;
        const float* wr = Ww + (size_t)u * UNITS + lane * 8;
        a = *(const float4*)wr;
        b = *(const float4*)(wr + 4);
        d = wave_reduce_add(dot8(a, b, v0, v1));
        if (lane == 0) ws[OFF_WV + u] = d;
    }

    if (blockIdx.x == 0) {
        float part = 0.f;
        for (int v = tid; v < UNITS; v += 256) part += (Wb[v] + Ub[v]) * Vw[v];
        part = wave_reduce_add(part);
        __shared__ float wred[4];
        if (lane == 0) wred[wave] = part;
        __syncthreads();
        if (tid == 0) ws[OFF_CB] = wred[0] + wred[1] + wred[2] + wred[3] + Vb[0];
    }

    __syncthreads();  // this block's wv rows visible block-wide (same-CU L1)

    // pp[b][blk] = sum_{j=0..15} s_prev[b, rowbase+j] * wv[rowbase+j]
    int b = tid >> 3;      // 0..31
    int g = tid & 7;       // 0..7 -> j = g, g+8
    int ua = rowbase + g, ub = rowbase + g + 8;
    float p = s_prev[(size_t)b * UNITS + ua] * ws[OFF_WV + ua]
            + s_prev[(size_t)b * UNITS + ub] * ws[OFF_WV + ub];
    p += __shfl_xor(p, 1);
    p += __shfl_xor(p, 2);
    p += __shfl_xor(p, 4);
    if (g == 0) ws[OFF_PP + b * 32 + blockIdx.x] = p;
}

// K1 (32x32 blocks): stream h once. p=exp(tanh(h.uv+pb)) unnormalized to the
// output weights region; partial Z and partial context to ws. No fences.
__global__ __launch_bounds__(256) void k_main(const float* __restrict__ h,
                                              float* __restrict__ ws,
                                              float* __restrict__ out) {
    int chunk = blockIdx.x, b = blockIdx.y;
    int tid = threadIdx.x, wave = tid >> 6, lane = tid & 63;

    __shared__ float pbsh;
    {
        float p = (lane < 32) ? ws[OFF_PP + b * 32 + lane] : 0.f;
        p = wave_reduce_add(p);
        if (tid == 0) pbsh = p + ws[OFF_CB];
    }
    float4 u0 = *(const float4*)(ws + OFF_UV + lane * 8);
    float4 u1 = *(const float4*)(ws + OFF_UV + lane * 8 + 4);
    __syncthreads();
    float pb = pbsh;

    float4 acc0 = make_float4(0.f, 0.f, 0.f, 0.f);
    float4 acc1 = make_float4(0.f, 0.f, 0.f, 0.f);
    float zs = 0.f;

    const float* hb = h + ((size_t)b * SEQ + (size_t)chunk * RPC) * UNITS + lane * 8;
    float* pout = out + (size_t)BATCH * UNITS + (size_t)b * SEQ + (size_t)chunk * RPC;

    for (int r = wave; r < RPC; r += 8) {
        const float* r0 = hb + (size_t)r * UNITS;
        const float* r1 = hb + (size_t)(r + 4) * UNITS;
        float4 a0 = *(const float4*)r0;
        float4 b0 = *(const float4*)(r0 + 4);
        float4 a1 = *(const float4*)r1;
        float4 b1 = *(const float4*)(r1 + 4);

        float d0 = dot8(a0, b0, u0, u1);
        float d1 = dot8(a1, b1, u0, u1);
#pragma unroll
        for (int off = 32; off >= 1; off >>= 1) {
            d0 += __shfl_xor(d0, off);
            d1 += __shfl_xor(d1, off);
        }
        float w0 = __expf(tanhf(d0 + pb));
        float w1 = __expf(tanhf(d1 + pb));
        if (lane == 0) { pout[r] = w0; pout[r + 4] = w1; }
        zs += w0 + w1;
        acc0.x += w0 * a0.x + w1 * a1.x;
        acc0.y += w0 * a0.y + w1 * a1.y;
        acc0.z += w0 * a0.z + w1 * a1.z;
        acc0.w += w0 * a0.w + w1 * a1.w;
        acc1.x += w0 * b0.x + w1 * b1.x;
        acc1.y += w0 * b0.y + w1 * b1.y;
        acc1.z += w0 * b0.z + w1 * b1.z;
        acc1.w += w0 * b0.w + w1 * b1.w;
    }

    __shared__ float lctx[4][UNITS];
    __shared__ float lsum[4];
    *(float4*)&lctx[wave][lane * 8]     = acc0;
    *(float4*)&lctx[wave][lane * 8 + 4] = acc1;
    if (lane == 0) lsum[wave] = zs;
    __syncthreads();

    float* pc = ws + OFF_PCTX + ((size_t)(b * CHUNKS + chunk)) * UNITS;
    for (int col = tid; col < UNITS; col += 256)
        pc[col] = lctx[0][col] + lctx[1][col] + lctx[2][col] + lctx[3][col];
    if (tid == 0)
        ws[OFF_PSUM + b * CHUNKS + chunk] = lsum[0] + lsum[1] + lsum[2] + lsum[3];
}

// K2 (256 blocks): block = (b, slice). Z from psum (redundant per block),
// context slice of 64 cols, scale 512 weights in place.
__global__ __launch_bounds__(256) void k_final(const float* __restrict__ ws,
                                               float* __restrict__ out) {
    int blk = blockIdx.x;
    int b = blk >> 3, sl = blk & 7;
    int tid = threadIdx.x;

    __shared__ float zsh;
    if (tid < 64) {
        float z = (tid < CHUNKS) ? ws[OFF_PSUM + b * CHUNKS + tid] : 0.f;
        z = wave_reduce_add(z);
        if (tid == 0) zsh = 1.0f / z;
    }
    __syncthreads();
    float rz = zsh;

    int col = sl * 64 + (tid & 63);
    int grp = tid >> 6;
    float s = 0.f;
#pragma unroll
    for (int c = 0; c < 8; ++c)
        s += ws[OFF_PCTX + (size_t)(b * CHUNKS + grp * 8 + c) * UNITS + col];
    __shared__ float red[4][64];
    red[grp][tid & 63] = s;
    __syncthreads();
    if (tid < 64)
        out[(size_t)b * UNITS + sl * 64 + tid] =
            (red[0][tid] + red[1][tid] + red[2][tid] + red[3][tid]) * rz;

    float* wout = out + (size_t)BATCH * UNITS + (size_t)b * SEQ + sl * 512;
#pragma unroll
    for (int i = tid; i < 512; i += 256) wout[i] *= rz;
}

extern "C" void kernel_launch(void* const* d_in, const int* in_sizes, int n_in,
                              void* d_out, int out_size, void* d_ws, size_t ws_size,
                              hipStream_t stream) {
    (void)in_sizes; (void)n_in; (void)out_size; (void)ws_size;
    const float* s_prev = (const float*)d_in[0];
    const float* h      = (const float*)d_in[1];
    const float* Ww     = (const float*)d_in[2];
    const float* Wb     = (const float*)d_in[3];
    const float* Uw     = (const float*)d_in[4];
    const float* Ub     = (const float*)d_in[5];
    const float* Vw     = (const float*)d_in[6];
    const float* Vb     = (const float*)d_in[7];
    float* out = (float*)d_out;
    float* ws  = (float*)d_ws;

    hipLaunchKernelGGL(k_prep,  dim3(32),            dim3(256), 0, stream,
                       Ww, Uw, Vw, Wb, Ub, Vb, s_prev, ws);
    hipLaunchKernelGGL(k_main,  dim3(CHUNKS, BATCH), dim3(256), 0, stream,
                       h, ws, out);
    hipLaunchKernelGGL(k_final, dim3(256),           dim3(256), 0, stream,
                       ws, out);
}